// Round 1
// baseline (896.015 us; speedup 1.0000x reference)
//
#include <hip/hip_runtime.h>

#define NB 8
#define NC 256
#define NL 2048
#define SCALE 0.0625f   // C^-0.5 = 1/16

// ---------------------------------------------------------------------------
// Kernel 1: fused QKV projection.  q/k/v[b,o,l] = sum_c W[o,c] x[b,c,l] + bias
// grid (L/64, C/64, B), block 256.  4x4 (o x l) micro-tile per thread.
// ---------------------------------------------------------------------------
__global__ __launch_bounds__(256, 1) void qkv_kernel(
    const float* __restrict__ x,
    const float* __restrict__ Wq, const float* __restrict__ bq,
    const float* __restrict__ Wk, const float* __restrict__ bk,
    const float* __restrict__ Wv, const float* __restrict__ bv,
    float* __restrict__ q, float* __restrict__ k, float* __restrict__ v)
{
    const int b  = blockIdx.z;
    const int o0 = blockIdx.y * 64;
    const int l0 = blockIdx.x * 64;
    const int t  = threadIdx.x;
    const int tx = t & 15;        // l micro-tile index
    const int ty = t >> 4;        // o micro-tile index

    __shared__ float xs[16][64];                    // [c][l]
    __shared__ float wqs[16][64];                   // [c][o]  (transposed)
    __shared__ float wks[16][64];
    __shared__ float wvs[16][64];

    float aq[4][4] = {}, ak[4][4] = {}, av[4][4] = {};

    const int wr  = t >> 2;   // 0..63  o_local for W staging
    const int wc4 = t & 3;    // 0..3   c float4-group for W staging
    const int xc  = t >> 4;   // 0..15  c row for x staging
    const int xj  = t & 15;   // 0..15  l float4-group for x staging

    for (int c0 = 0; c0 < NC; c0 += 16) {
        __syncthreads();   // previous chunk fully consumed
        // stage x chunk [16c x 64l], coalesced float4
        *(((float4*)&xs[xc][0]) + xj) =
            *(const float4*)&x[((size_t)(b * NC + c0 + xc)) * NL + l0 + xj * 4];
        // stage W chunks transposed to [c][o] so compute reads are float4
        {
            float4 w;
            w = *(const float4*)&Wq[(size_t)(o0 + wr) * NC + c0 + wc4 * 4];
            wqs[wc4*4+0][wr] = w.x; wqs[wc4*4+1][wr] = w.y;
            wqs[wc4*4+2][wr] = w.z; wqs[wc4*4+3][wr] = w.w;
            w = *(const float4*)&Wk[(size_t)(o0 + wr) * NC + c0 + wc4 * 4];
            wks[wc4*4+0][wr] = w.x; wks[wc4*4+1][wr] = w.y;
            wks[wc4*4+2][wr] = w.z; wks[wc4*4+3][wr] = w.w;
            w = *(const float4*)&Wv[(size_t)(o0 + wr) * NC + c0 + wc4 * 4];
            wvs[wc4*4+0][wr] = w.x; wvs[wc4*4+1][wr] = w.y;
            wvs[wc4*4+2][wr] = w.z; wvs[wc4*4+3][wr] = w.w;
        }
        __syncthreads();
        #pragma unroll
        for (int cc = 0; cc < 16; ++cc) {
            float4 xv  = *(((const float4*)&xs[cc][0])  + tx);
            float4 wq4 = *(((const float4*)&wqs[cc][0]) + ty);
            float4 wk4 = *(((const float4*)&wks[cc][0]) + ty);
            float4 wv4 = *(((const float4*)&wvs[cc][0]) + ty);
            float xa[4] = {xv.x,  xv.y,  xv.z,  xv.w};
            float qa[4] = {wq4.x, wq4.y, wq4.z, wq4.w};
            float ka[4] = {wk4.x, wk4.y, wk4.z, wk4.w};
            float va[4] = {wv4.x, wv4.y, wv4.z, wv4.w};
            #pragma unroll
            for (int i = 0; i < 4; ++i)
                #pragma unroll
                for (int j = 0; j < 4; ++j) {
                    aq[i][j] += qa[i] * xa[j];
                    ak[i][j] += ka[i] * xa[j];
                    av[i][j] += va[i] * xa[j];
                }
        }
    }

    // epilogue: add bias, float4 stores
    #pragma unroll
    for (int i = 0; i < 4; ++i) {
        const int o = o0 + ty * 4 + i;
        const float bqv = bq[o], bkv = bk[o], bvv = bv[o];
        const size_t base = ((size_t)(b * NC + o)) * NL + l0 + tx * 4;
        float4 oq = make_float4(aq[i][0]+bqv, aq[i][1]+bqv, aq[i][2]+bqv, aq[i][3]+bqv);
        float4 ok = make_float4(ak[i][0]+bkv, ak[i][1]+bkv, ak[i][2]+bkv, ak[i][3]+bkv);
        float4 ov = make_float4(av[i][0]+bvv, av[i][1]+bvv, av[i][2]+bvv, av[i][3]+bvv);
        *(float4*)&q[base] = oq;
        *(float4*)&k[base] = ok;
        *(float4*)&v[base] = ov;
    }
}

// ---------------------------------------------------------------------------
// Kernel 2: flash-style attention + residual.
// grid (L/64, B), block 256; one block = one (batch, 64-query tile).
// No max-subtraction: logits ~N(0,0.64), |s|max << fp32 exp range.
// ---------------------------------------------------------------------------
__global__ __launch_bounds__(256, 1) void attn_kernel(
    const float* __restrict__ q, const float* __restrict__ k,
    const float* __restrict__ v, const float* __restrict__ x,
    float* __restrict__ out)
{
    const int b    = blockIdx.y;
    const int l0   = blockIdx.x * 64;
    const int t    = threadIdx.x;
    const int tx   = t & 15;          // phase1: j-group / phase3: c-group
    const int ty   = t >> 4;          // phase1+3: i-group (rows l0+ty*4..+3)
    const int lane = t & 63;
    const int rowgrp = lane & 48;     // first lane of this 16-lane row group

    __shared__ float Qs[NC][64];        // [c][i]   64 KB, loaded once
    __shared__ float Ks[32][64];        // [cc][j]   8 KB, streamed
    __shared__ float VsT[64][NC + 4];   // [j][c]   66.6 KB (pad 4 -> 2-way reads)
    __shared__ float T[64][65];         // epilogue staging
    __shared__ float denomS[64];

    // ---- load Q tile once (coalesced float4) ----
    #pragma unroll
    for (int qq = 0; qq < 16; ++qq) {
        const int f = t + 256 * qq;
        const int c = f >> 4, i4 = f & 15;
        *(((float4*)&Qs[c][0]) + i4) =
            *(const float4*)&q[((size_t)(b * NC + c)) * NL + l0 + i4 * 4];
    }
    if (t < 64) denomS[t] = 0.0f;

    float ctx[4][4][4] = {};   // [g][cx][ii]: c = g*64+tx*4+cx, row i = ty*4+ii

    for (int mt = 0; mt < 32; ++mt) {
        const int m0 = mt * 64;
        __syncthreads();   // previous tile's VsT/Ks reads complete

        // ---- stage V tile transposed: VsT[j][c] ----
        #pragma unroll
        for (int qq = 0; qq < 16; ++qq) {
            const int f = t + 256 * qq;
            const int c = f >> 4, j4 = f & 15;
            float4 vv = *(const float4*)&v[((size_t)(b * NC + c)) * NL + m0 + j4 * 4];
            VsT[j4*4+0][c] = vv.x;
            VsT[j4*4+1][c] = vv.y;
            VsT[j4*4+2][c] = vv.z;
            VsT[j4*4+3][c] = vv.w;
        }

        // ---- phase 1: S = Q^T K over c-chunks of 32 ----
        float s[4][4] = {};
        for (int ch = 0; ch < 8; ++ch) {
            if (ch) __syncthreads();     // previous Ks chunk consumed
            #pragma unroll
            for (int h = 0; h < 2; ++h) {
                const int f = t + 256 * h;
                const int cc = f >> 4, j4 = f & 15;
                *(((float4*)&Ks[cc][0]) + j4) =
                    *(const float4*)&k[((size_t)(b * NC + ch * 32 + cc)) * NL + m0 + j4 * 4];
            }
            __syncthreads();             // Ks chunk ready (also fences VsT on ch==0 path)
            #pragma unroll
            for (int cc = 0; cc < 32; ++cc) {
                float4 q4 = *(((const float4*)&Qs[ch * 32 + cc][0]) + ty);
                float4 k4 = *(((const float4*)&Ks[cc][0]) + tx);
                float qa[4] = {q4.x, q4.y, q4.z, q4.w};
                float ka[4] = {k4.x, k4.y, k4.z, k4.w};
                #pragma unroll
                for (int ii = 0; ii < 4; ++ii)
                    #pragma unroll
                    for (int jj = 0; jj < 4; ++jj)
                        s[ii][jj] += qa[ii] * ka[jj];
            }
        }

        // ---- phase 2: exponentiate, accumulate row denominators ----
        float p[4][4], rsum[4];
        #pragma unroll
        for (int ii = 0; ii < 4; ++ii) {
            rsum[ii] = 0.0f;
            #pragma unroll
            for (int jj = 0; jj < 4; ++jj) {
                float e = __expf(s[ii][jj] * SCALE);
                p[ii][jj] = e;
                rsum[ii] += e;
            }
        }
        #pragma unroll
        for (int ii = 0; ii < 4; ++ii) {
            rsum[ii] += __shfl_down(rsum[ii], 8, 16);
            rsum[ii] += __shfl_down(rsum[ii], 4, 16);
            rsum[ii] += __shfl_down(rsum[ii], 2, 16);
            rsum[ii] += __shfl_down(rsum[ii], 1, 16);
        }
        if (tx == 0) {
            #pragma unroll
            for (int ii = 0; ii < 4; ++ii) denomS[ty * 4 + ii] += rsum[ii];
        }

        // ---- phase 3: ctx[c][i] += sum_j P[i][j] * V[c][j] ----
        // P broadcast in-register via shuffles within the 16-lane row group.
        for (int js = 0; js < 16; ++js) {
            const int src = rowgrp + js;
            #pragma unroll
            for (int jj = 0; jj < 4; ++jj) {
                float pja[4];
                pja[0] = __shfl(p[0][jj], src, 64);
                pja[1] = __shfl(p[1][jj], src, 64);
                pja[2] = __shfl(p[2][jj], src, 64);
                pja[3] = __shfl(p[3][jj], src, 64);
                const int j = js * 4 + jj;
                #pragma unroll
                for (int g = 0; g < 4; ++g) {
                    float4 vv = *(const float4*)&VsT[j][g * 64 + tx * 4];
                    float va[4] = {vv.x, vv.y, vv.z, vv.w};
                    #pragma unroll
                    for (int cx = 0; cx < 4; ++cx)
                        #pragma unroll
                        for (int ii = 0; ii < 4; ++ii)
                            ctx[g][cx][ii] += va[cx] * pja[ii];
                }
            }
        }
    }

    // ---- epilogue: divide by denom, add residual, coalesced stores via LDS ----
    __syncthreads();
    float dinv[4];
    #pragma unroll
    for (int ii = 0; ii < 4; ++ii) dinv[ii] = 1.0f / denomS[ty * 4 + ii];

    const int colg = t >> 6;     // 0..3
    const int col  = t & 63;
    #pragma unroll
    for (int g = 0; g < 4; ++g) {
        #pragma unroll
        for (int cx = 0; cx < 4; ++cx)
            #pragma unroll
            for (int ii = 0; ii < 4; ++ii)
                T[tx * 4 + cx][ty * 4 + ii] = ctx[g][cx][ii] * dinv[ii];
        __syncthreads();
        #pragma unroll
        for (int rr = 0; rr < 16; ++rr) {
            const int c_local = colg * 16 + rr;
            const int cg = g * 64 + c_local;
            const size_t idx = ((size_t)(b * NC + cg)) * NL + l0 + col;
            out[idx] = T[c_local][col] + x[idx];
        }
        __syncthreads();
    }
}

// ---------------------------------------------------------------------------
extern "C" void kernel_launch(void* const* d_in, const int* in_sizes, int n_in,
                              void* d_out, int out_size, void* d_ws, size_t ws_size,
                              hipStream_t stream) {
    const float* x  = (const float*)d_in[0];
    const float* Wq = (const float*)d_in[1];
    const float* bq = (const float*)d_in[2];
    const float* Wk = (const float*)d_in[3];
    const float* bk = (const float*)d_in[4];
    const float* Wv = (const float*)d_in[5];
    const float* bv = (const float*)d_in[6];
    float* out = (float*)d_out;

    const size_t plane = (size_t)NB * NC * NL;   // 4.19M floats
    float* q = (float*)d_ws;
    float* k = q + plane;
    float* v = k + plane;

    dim3 gq(NL / 64, NC / 64, NB);   // (32, 4, 8)
    qkv_kernel<<<gq, 256, 0, stream>>>(x, Wq, bq, Wk, bk, Wv, bv, q, k, v);

    dim3 ga(NL / 64, NB);            // (32, 8) = 256 blocks
    attn_kernel<<<ga, 256, 0, stream>>>(q, k, v, x, out);
}

// Round 2
// 230.095 us; speedup vs baseline: 3.8941x; 3.8941x over previous
//
#include <hip/hip_runtime.h>

#define NB 8
#define NC 256
#define NL 2048
#define SCALE 0.0625f   // C^-0.5 = 1/16

typedef __attribute__((ext_vector_type(8))) __bf16 bf16x8;
typedef __attribute__((ext_vector_type(4))) float f32x4;
typedef __attribute__((ext_vector_type(4))) unsigned int u32x4;
typedef __attribute__((ext_vector_type(4))) unsigned short u16x4;

// round-to-nearest-even fp32 -> bf16 bits
static __device__ __forceinline__ unsigned short f2b(float f) {
    unsigned int u = __builtin_bit_cast(unsigned int, f);
    u += 0x7fffu + ((u >> 16) & 1u);
    return (unsigned short)(u >> 16);
}

// ---------------------------------------------------------------------------
// Kernel 1: fused QKV projection (fp32 compute), bf16 outputs:
//   qT,kT: [B][L][C]  (transposed -> MFMA A/B frags are contiguous-8 loads)
//   v:     [B][C][L]  (natural   -> PV B-operand layout)
// ---------------------------------------------------------------------------
__global__ __launch_bounds__(256, 1) void qkv_kernel(
    const float* __restrict__ x,
    const float* __restrict__ Wq, const float* __restrict__ bq,
    const float* __restrict__ Wk, const float* __restrict__ bk,
    const float* __restrict__ Wv, const float* __restrict__ bv,
    unsigned short* __restrict__ qT, unsigned short* __restrict__ kT,
    unsigned short* __restrict__ vo)
{
    const int b  = blockIdx.z;
    const int o0 = blockIdx.y * 64;
    const int l0 = blockIdx.x * 64;
    const int t  = threadIdx.x;
    const int tx = t & 15;        // l micro-tile index
    const int ty = t >> 4;        // o micro-tile index

    __shared__ float xs[16][64];
    __shared__ float wqs[16][64];
    __shared__ float wks[16][64];
    __shared__ float wvs[16][64];

    float aq[4][4] = {}, ak[4][4] = {}, av[4][4] = {};

    const int wr  = t >> 2;
    const int wc4 = t & 3;
    const int xc  = t >> 4;
    const int xj  = t & 15;

    for (int c0 = 0; c0 < NC; c0 += 16) {
        __syncthreads();
        *(((float4*)&xs[xc][0]) + xj) =
            *(const float4*)&x[((size_t)(b * NC + c0 + xc)) * NL + l0 + xj * 4];
        {
            float4 w;
            w = *(const float4*)&Wq[(size_t)(o0 + wr) * NC + c0 + wc4 * 4];
            wqs[wc4*4+0][wr] = w.x; wqs[wc4*4+1][wr] = w.y;
            wqs[wc4*4+2][wr] = w.z; wqs[wc4*4+3][wr] = w.w;
            w = *(const float4*)&Wk[(size_t)(o0 + wr) * NC + c0 + wc4 * 4];
            wks[wc4*4+0][wr] = w.x; wks[wc4*4+1][wr] = w.y;
            wks[wc4*4+2][wr] = w.z; wks[wc4*4+3][wr] = w.w;
            w = *(const float4*)&Wv[(size_t)(o0 + wr) * NC + c0 + wc4 * 4];
            wvs[wc4*4+0][wr] = w.x; wvs[wc4*4+1][wr] = w.y;
            wvs[wc4*4+2][wr] = w.z; wvs[wc4*4+3][wr] = w.w;
        }
        __syncthreads();
        #pragma unroll
        for (int cc = 0; cc < 16; ++cc) {
            float4 xv  = *(((const float4*)&xs[cc][0])  + tx);
            float4 wq4 = *(((const float4*)&wqs[cc][0]) + ty);
            float4 wk4 = *(((const float4*)&wks[cc][0]) + ty);
            float4 wv4 = *(((const float4*)&wvs[cc][0]) + ty);
            float xa[4] = {xv.x,  xv.y,  xv.z,  xv.w};
            float qa[4] = {wq4.x, wq4.y, wq4.z, wq4.w};
            float ka[4] = {wk4.x, wk4.y, wk4.z, wk4.w};
            float va[4] = {wv4.x, wv4.y, wv4.z, wv4.w};
            #pragma unroll
            for (int i = 0; i < 4; ++i)
                #pragma unroll
                for (int j = 0; j < 4; ++j) {
                    aq[i][j] += qa[i] * xa[j];
                    ak[i][j] += ka[i] * xa[j];
                    av[i][j] += va[i] * xa[j];
                }
        }
    }

    const int o_base = o0 + ty * 4;
    float bqv[4], bkv[4], bvv[4];
    #pragma unroll
    for (int i = 0; i < 4; ++i) {
        bqv[i] = bq[o_base + i];
        bkv[i] = bk[o_base + i];
        bvv[i] = bv[o_base + i];
    }
    // qT,kT [B][L][C]: per l, 4 contiguous c  (8B stores)
    #pragma unroll
    for (int j = 0; j < 4; ++j) {
        const int l = l0 + tx * 4 + j;
        const size_t rb = ((size_t)b * NL + l) * NC + o_base;
        u16x4 pq, pk;
        #pragma unroll
        for (int i = 0; i < 4; ++i) {
            pq[i] = f2b(aq[i][j] + bqv[i]);
            pk[i] = f2b(ak[i][j] + bkv[i]);
        }
        *(u16x4*)&qT[rb] = pq;
        *(u16x4*)&kT[rb] = pk;
    }
    // v [B][C][L]: per c, 4 contiguous l
    #pragma unroll
    for (int i = 0; i < 4; ++i) {
        const size_t vb_ = ((size_t)(b * NC + o_base + i)) * NL + l0 + tx * 4;
        u16x4 pv;
        #pragma unroll
        for (int j = 0; j < 4; ++j) pv[j] = f2b(av[i][j] + bvv[i]);
        *(u16x4*)&vo[vb_] = pv;
    }
}

// ---------------------------------------------------------------------------
// Kernel 2: MFMA flash attention + residual.
// grid (L/64, B), 256 thr = 4 waves; wave w owns query rows w*16..w*16+15.
// K/V key-tiles (64) staged to LDS via global_load_lds(16B) with XOR-chunk
// swizzle (applied on the GLOBAL address side; LDS side is lane-contiguous).
// ---------------------------------------------------------------------------
__global__ __launch_bounds__(256, 1) void attn_kernel(
    const unsigned short* __restrict__ qT,
    const unsigned short* __restrict__ kT,
    const unsigned short* __restrict__ v,
    const float* __restrict__ x,
    float* __restrict__ out)
{
    const int b    = blockIdx.y;
    const int l0   = blockIdx.x * 64;
    const int t    = threadIdx.x;
    const int w    = t >> 6;
    const int lane = t & 63;
    const int ln15 = lane & 15;
    const int quad = lane >> 4;

    __shared__ __align__(16) unsigned short Klds[64 * 256]; // [n][c] swz, 32 KB
    __shared__ __align__(16) unsigned short Vlds[256 * 64]; // [c][j] swz, 32 KB
    __shared__ __align__(16) unsigned short Plds[64 * 64];  // [i][j] swz,  8 KB
    __shared__ float denom[64];
    __shared__ __align__(16) float T[64][68];               // epilogue staging

    // ---- Q fragments resident in registers: rows l0 + w*16 + ln15 ----
    bf16x8 qf[8];
    {
        const size_t qrow = ((size_t)b * NL + l0 + w * 16 + ln15) * NC;
        #pragma unroll
        for (int kt = 0; kt < 8; ++kt)
            qf[kt] = __builtin_bit_cast(bf16x8,
                        *(const u32x4*)&qT[qrow + kt * 32 + quad * 8]);
    }
    if (t < 64) denom[t] = 0.0f;

    f32x4 ctx[16];
    #pragma unroll
    for (int i = 0; i < 16; ++i) ctx[i] = f32x4{0.f, 0.f, 0.f, 0.f};

    for (int mt = 0; mt < 32; ++mt) {
        const int m0 = mt * 64;
        __syncthreads();   // previous tile's LDS reads complete

        // ---- stage K tile: 64 rows x 512B, chunk g at pos g^(n&15) ----
        #pragma unroll
        for (int s = 0; s < 8; ++s) {
            const int il = w * 8 + s;
            const int n  = il * 2 + (lane >> 5);
            const int p  = lane & 31;
            const int g  = p ^ (n & 15);
            const unsigned short* gp =
                &kT[((size_t)b * NL + m0 + n) * NC + g * 8];
            __builtin_amdgcn_global_load_lds(
                (const __attribute__((address_space(1))) unsigned int*)gp,
                (__attribute__((address_space(3))) unsigned int*)&Klds[il * 512],
                16, 0, 0);
        }
        // ---- stage V tile: 256 rows x 128B, chunk g at pos g^(c&7) ----
        #pragma unroll
        for (int s = 0; s < 8; ++s) {
            const int il = w * 8 + s;
            const int c  = il * 8 + (lane >> 3);
            const int p  = lane & 7;
            const int g  = p ^ (c & 7);
            const unsigned short* gp =
                &v[((size_t)(b * NC + c)) * NL + m0 + g * 8];
            __builtin_amdgcn_global_load_lds(
                (const __attribute__((address_space(1))) unsigned int*)gp,
                (__attribute__((address_space(3))) unsigned int*)&Vlds[il * 512],
                16, 0, 0);
        }
        __syncthreads();   // drains vmcnt: tiles visible

        // ---- S = Q^T K  (per wave: 16 rows x 64 cols) ----
        f32x4 sacc[4];
        #pragma unroll
        for (int nt = 0; nt < 4; ++nt) sacc[nt] = f32x4{0.f, 0.f, 0.f, 0.f};
        #pragma unroll
        for (int nt = 0; nt < 4; ++nt) {
            const int n = nt * 16 + ln15;
            #pragma unroll
            for (int kt = 0; kt < 8; ++kt) {
                const int p = (kt * 4 + quad) ^ ln15;
                bf16x8 bf = __builtin_bit_cast(bf16x8,
                              *(const u32x4*)&Klds[n * 256 + p * 8]);
                sacc[nt] = __builtin_amdgcn_mfma_f32_16x16x32_bf16(
                               qf[kt], bf, sacc[nt], 0, 0, 0);
            }
        }

        // ---- exp (no max-sub), row sums, P -> LDS (bf16, swizzled) ----
        float rs[4] = {0.f, 0.f, 0.f, 0.f};
        #pragma unroll
        for (int nt = 0; nt < 4; ++nt) {
            #pragma unroll
            for (int r = 0; r < 4; ++r) {
                float e = __expf(sacc[nt][r] * SCALE);
                rs[r] += e;
                const int ip = w * 16 + quad * 4 + r;     // P row (query)
                const int j  = nt * 16 + ln15;            // P col (key)
                const int pc = (j >> 3) ^ (ip & 7);       // swizzled chunk
                Plds[ip * 64 + pc * 8 + (j & 7)] = f2b(e);
            }
        }
        #pragma unroll
        for (int r = 0; r < 4; ++r) {
            rs[r] += __shfl_xor(rs[r], 1, 64);
            rs[r] += __shfl_xor(rs[r], 2, 64);
            rs[r] += __shfl_xor(rs[r], 4, 64);
            rs[r] += __shfl_xor(rs[r], 8, 64);
        }
        if (ln15 == 0) {
            #pragma unroll
            for (int r = 0; r < 4; ++r) denom[w * 16 + quad * 4 + r] += rs[r];
        }

        // ---- PV: ctx[i][c] += P[i][j] * V[c][j]  (wave-local P) ----
        bf16x8 pf[2];
        {
            const int m = w * 16 + ln15;
            #pragma unroll
            for (int kt = 0; kt < 2; ++kt) {
                const int p = (kt * 4 + quad) ^ (m & 7);
                pf[kt] = __builtin_bit_cast(bf16x8,
                           *(const u32x4*)&Plds[m * 64 + p * 8]);
            }
        }
        #pragma unroll
        for (int ct = 0; ct < 16; ++ct) {
            const int c = ct * 16 + ln15;
            #pragma unroll
            for (int kt = 0; kt < 2; ++kt) {
                const int p = (kt * 4 + quad) ^ (c & 7);
                bf16x8 vb = __builtin_bit_cast(bf16x8,
                              *(const u32x4*)&Vlds[c * 64 + p * 8]);
                ctx[ct] = __builtin_amdgcn_mfma_f32_16x16x32_bf16(
                              pf[kt], vb, ctx[ct], 0, 0, 0);
            }
        }
    }

    // ---- epilogue: normalize, residual, coalesced stores via LDS ----
    __syncthreads();
    float dinv[4];
    #pragma unroll
    for (int r = 0; r < 4; ++r) dinv[r] = 1.0f / denom[w * 16 + quad * 4 + r];

    const int col  = t & 63;
    const int colg = t >> 6;
    for (int gq = 0; gq < 4; ++gq) {
        __syncthreads();
        #pragma unroll
        for (int ctl = 0; ctl < 4; ++ctl) {
            const int ct = gq * 4 + ctl;
            f32x4 val;
            #pragma unroll
            for (int r = 0; r < 4; ++r) val[r] = ctx[ct][r] * dinv[r];
            *(f32x4*)&T[ctl * 16 + ln15][w * 16 + quad * 4] = val;
        }
        __syncthreads();
        #pragma unroll
        for (int rr = 0; rr < 16; ++rr) {
            const int cl = colg * 16 + rr;
            const size_t idx = ((size_t)(b * NC + gq * 64 + cl)) * NL + l0 + col;
            out[idx] = T[cl][col] + x[idx];
        }
    }
}

// ---------------------------------------------------------------------------
extern "C" void kernel_launch(void* const* d_in, const int* in_sizes, int n_in,
                              void* d_out, int out_size, void* d_ws, size_t ws_size,
                              hipStream_t stream) {
    const float* x  = (const float*)d_in[0];
    const float* Wq = (const float*)d_in[1];
    const float* bq = (const float*)d_in[2];
    const float* Wk = (const float*)d_in[3];
    const float* bk = (const float*)d_in[4];
    const float* Wv = (const float*)d_in[5];
    const float* bv = (const float*)d_in[6];
    float* out = (float*)d_out;

    const size_t plane = (size_t)NB * NC * NL;
    unsigned short* qT = (unsigned short*)d_ws;
    unsigned short* kT = qT + plane;
    unsigned short* v  = kT + plane;

    dim3 gq(NL / 64, NC / 64, NB);   // (32, 4, 8)
    qkv_kernel<<<gq, 256, 0, stream>>>(x, Wq, bq, Wk, bk, Wv, bv, qT, kT, v);

    dim3 ga(NL / 64, NB);            // (32, 8) = 256 blocks
    attn_kernel<<<ga, 256, 0, stream>>>(qT, kT, v, x, out);
}

// Round 3
// 180.514 us; speedup vs baseline: 4.9637x; 1.2747x over previous
//
#include <hip/hip_runtime.h>

#define NB 8
#define NC 256
#define NL 2048
#define SCALE 0.0625f   // C^-0.5 = 1/16

typedef __attribute__((ext_vector_type(8))) __bf16 bf16x8;
typedef __attribute__((ext_vector_type(4))) float f32x4;
typedef __attribute__((ext_vector_type(4))) unsigned int u32x4;
typedef __attribute__((ext_vector_type(4))) unsigned short u16x4;
typedef __attribute__((ext_vector_type(8))) unsigned short u16x8;

// round-to-nearest-even fp32 -> bf16 bits
static __device__ __forceinline__ unsigned short f2b(float f) {
    unsigned int u = __builtin_bit_cast(unsigned int, f);
    u += 0x7fffu + ((u >> 16) & 1u);
    return (unsigned short)(u >> 16);
}

// ---------------------------------------------------------------------------
// Prep A: Wq/Wk/Wv fp32 -> bf16, concatenated [3][256][256].
// grid 192, block 256, 4 elems/thread.
// ---------------------------------------------------------------------------
__global__ void wconv_kernel(const float* __restrict__ Wq,
                             const float* __restrict__ Wk,
                             const float* __restrict__ Wv,
                             unsigned short* __restrict__ Wbf)
{
    const int base = (blockIdx.x * 256 + threadIdx.x) * 4;
    const int mat  = base >> 16;
    const int off  = base & 65535;
    const float* W = (mat == 0) ? Wq : (mat == 1) ? Wk : Wv;
    float4 w = *(const float4*)&W[off];
    u16x4 p = {f2b(w.x), f2b(w.y), f2b(w.z), f2b(w.w)};
    *(u16x4*)&Wbf[base] = p;
}

// ---------------------------------------------------------------------------
// Prep B: x [B][C][L] fp32 -> xT [B][L][C] bf16 (transpose via LDS).
// grid (32, 4, 8), block 256.
// ---------------------------------------------------------------------------
__global__ __launch_bounds__(256, 2) void xprep_kernel(
    const float* __restrict__ x, unsigned short* __restrict__ xT)
{
    const int b  = blockIdx.z;
    const int c0 = blockIdx.y * 64;
    const int l0 = blockIdx.x * 64;
    const int t  = threadIdx.x;

    __shared__ unsigned short Tr[64][68];

    #pragma unroll
    for (int p = 0; p < 4; ++p) {
        const int c  = p * 16 + (t >> 4);
        const int lg = t & 15;
        float4 xv = *(const float4*)&x[((size_t)(b * NC + c0 + c)) * NL + l0 + lg * 4];
        u16x4 pk = {f2b(xv.x), f2b(xv.y), f2b(xv.z), f2b(xv.w)};
        *(u16x4*)&Tr[c][lg * 4] = pk;
    }
    __syncthreads();
    #pragma unroll
    for (int j = 0; j < 2; ++j) {
        const int chunk = t + 256 * j;      // 0..511
        const int l  = chunk >> 3;
        const int ck = chunk & 7;
        u16x8 o;
        #pragma unroll
        for (int i = 0; i < 8; ++i) o[i] = Tr[ck * 8 + i][l];
        *(u16x8*)&xT[((size_t)(b * NL + l0 + l)) * NC + c0 + ck * 8] = o;
    }
}

// ---------------------------------------------------------------------------
// Kernel 1: QKV projection via MFMA.
// grid 768 linear -> (b = raw&7 for XCD L2 locality, mat, ltile). block 256.
// Outputs: qT,kT [B][L][C] bf16;  v [B][C][L] bf16.
// ---------------------------------------------------------------------------
__global__ __launch_bounds__(256, 2) void qkv_mfma(
    const unsigned short* __restrict__ xT,
    const unsigned short* __restrict__ Wbf,
    const float* __restrict__ bq, const float* __restrict__ bk,
    const float* __restrict__ bv,
    unsigned short* __restrict__ qT, unsigned short* __restrict__ kT,
    unsigned short* __restrict__ vo)
{
    const int raw = blockIdx.x;
    const int b   = raw & 7;          // XCD-pinned batch
    const int rem = raw >> 3;         // 0..95
    const int mat = rem >> 5;         // 0..2
    const int lt0 = (rem & 31) * 64;
    const int t    = threadIdx.x;
    const int w    = t >> 6;
    const int lane = t & 63;
    const int ln15 = lane & 15;
    const int quad = lane >> 4;

    __shared__ __align__(16) unsigned short XT[64 * 256];  // [l][c] swz, 32 KB
    __shared__ __align__(16) unsigned short WC[256 * 64];  // [o][c-chunk] swz, 32 KB

    const unsigned short* Wm = Wbf + mat * 65536;
    const float* bias = (mat == 0) ? bq : (mat == 1) ? bk : bv;

    // bias fragment preload (reused across lt)
    float bvals[4][4];
    #pragma unroll
    for (int ot = 0; ot < 4; ++ot)
        #pragma unroll
        for (int r = 0; r < 4; ++r)
            bvals[ot][r] = bias[w * 64 + ot * 16 + quad * 4 + r];

    // ---- stage XT once: 64 rows x 512B, chunk g at pos g^(n&15) ----
    #pragma unroll
    for (int s = 0; s < 8; ++s) {
        const int il = w * 8 + s;
        const int n  = il * 2 + (lane >> 5);
        const int p  = lane & 31;
        const int g  = p ^ (n & 15);
        const unsigned short* gp = &xT[((size_t)(b * NL + lt0 + n)) * NC + g * 8];
        __builtin_amdgcn_global_load_lds(
            (const __attribute__((address_space(1))) unsigned int*)gp,
            (__attribute__((address_space(3))) unsigned int*)&XT[il * 512],
            16, 0, 0);
    }

    f32x4 acc[4][4];   // [ot][lt]
    #pragma unroll
    for (int i = 0; i < 4; ++i)
        #pragma unroll
        for (int j = 0; j < 4; ++j) acc[i][j] = f32x4{0.f, 0.f, 0.f, 0.f};

    for (int k0 = 0; k0 < 4; ++k0) {       // c-chunk of 64
        if (k0) __syncthreads();           // WC consumed
        // ---- stage WC: 256 rows x 128B, chunk g at pos g^(o&7) ----
        #pragma unroll
        for (int s = 0; s < 8; ++s) {
            const int il = w * 8 + s;
            const int o  = il * 8 + (lane >> 3);
            const int p  = lane & 7;
            const int g  = p ^ (o & 7);
            const unsigned short* gp = &Wm[(size_t)o * NC + k0 * 64 + g * 8];
            __builtin_amdgcn_global_load_lds(
                (const __attribute__((address_space(1))) unsigned int*)gp,
                (__attribute__((address_space(3))) unsigned int*)&WC[il * 512],
                16, 0, 0);
        }
        __syncthreads();                   // drains vmcnt (covers XT on k0==0)

        #pragma unroll
        for (int ks = 0; ks < 2; ++ks) {
            bf16x8 xf[4];
            #pragma unroll
            for (int lt = 0; lt < 4; ++lt) {
                const int l  = lt * 16 + ln15;
                const int kc = k0 * 8 + ks * 4 + quad;
                const int pp = kc ^ (l & 15);
                xf[lt] = __builtin_bit_cast(bf16x8, *(const u32x4*)&XT[l * 256 + pp * 8]);
            }
            #pragma unroll
            for (int ot = 0; ot < 4; ++ot) {
                const int o  = w * 64 + ot * 16 + ln15;
                const int pp = (ks * 4 + quad) ^ (o & 7);
                bf16x8 wf = __builtin_bit_cast(bf16x8, *(const u32x4*)&WC[o * 64 + pp * 8]);
                #pragma unroll
                for (int lt = 0; lt < 4; ++lt)
                    acc[ot][lt] = __builtin_amdgcn_mfma_f32_16x16x32_bf16(
                                      wf, xf[lt], acc[ot][lt], 0, 0, 0);
            }
        }
    }

    // ---- epilogue: bias add, bf16 store ----
    if (mat < 2) {
        unsigned short* out = (mat == 0) ? qT : kT;
        #pragma unroll
        for (int ot = 0; ot < 4; ++ot) {
            const int o_base = w * 64 + ot * 16 + quad * 4;
            #pragma unroll
            for (int lt = 0; lt < 4; ++lt) {
                const int l = lt0 + lt * 16 + ln15;
                u16x4 pk;
                #pragma unroll
                for (int r = 0; r < 4; ++r)
                    pk[r] = f2b(acc[ot][lt][r] + bvals[ot][r]);
                *(u16x4*)&out[((size_t)(b * NL + l)) * NC + o_base] = pk;
            }
        }
    } else {
        #pragma unroll
        for (int ot = 0; ot < 4; ++ot)
            #pragma unroll
            for (int lt = 0; lt < 4; ++lt) {
                const int l = lt0 + lt * 16 + ln15;
                #pragma unroll
                for (int r = 0; r < 4; ++r) {
                    const int o = w * 64 + ot * 16 + quad * 4 + r;
                    vo[((size_t)(b * NC + o)) * NL + l] = f2b(acc[ot][lt][r] + bvals[ot][r]);
                }
            }
    }
}

// ---------------------------------------------------------------------------
// Kernel 2: MFMA flash attention + residual.
// grid 256 linear -> (b = raw&7 for XCD L2 locality, ltile). block 256.
// LDS: K(32K)+V(32K)+P(8K)+denom, epilogue T aliases K region -> 74 KB total,
// 2 blocks/CU (was 157 KB / 1 block).
// ---------------------------------------------------------------------------
__global__ __launch_bounds__(256, 2) void attn_kernel(
    const unsigned short* __restrict__ qT,
    const unsigned short* __restrict__ kT,
    const unsigned short* __restrict__ v,
    const float* __restrict__ x,
    float* __restrict__ out)
{
    const int raw  = blockIdx.x;
    const int b    = raw & 7;         // XCD-pinned batch
    const int l0   = (raw >> 3) * 64;
    const int t    = threadIdx.x;
    const int w    = t >> 6;
    const int lane = t & 63;
    const int ln15 = lane & 15;
    const int quad = lane >> 4;

    __shared__ __align__(16) char smem[73984];
    unsigned short* Klds = (unsigned short*)smem;            // 32 KB [n][c] swz
    unsigned short* Vlds = (unsigned short*)(smem + 32768);  // 32 KB [c][j] swz
    unsigned short* Plds = (unsigned short*)(smem + 65536);  //  8 KB [i][j] swz
    float*          denom = (float*)(smem + 73728);          // 256 B
    float (*T)[68] = (float(*)[68])smem;                     // epilogue, aliases Klds

    // ---- Q fragments resident in registers ----
    bf16x8 qf[8];
    {
        const size_t qrow = ((size_t)b * NL + l0 + w * 16 + ln15) * NC;
        #pragma unroll
        for (int kt = 0; kt < 8; ++kt)
            qf[kt] = __builtin_bit_cast(bf16x8,
                        *(const u32x4*)&qT[qrow + kt * 32 + quad * 8]);
    }
    if (t < 64) denom[t] = 0.0f;

    f32x4 ctx[16];
    #pragma unroll
    for (int i = 0; i < 16; ++i) ctx[i] = f32x4{0.f, 0.f, 0.f, 0.f};

    for (int mt = 0; mt < 32; ++mt) {
        const int m0 = mt * 64;
        __syncthreads();

        #pragma unroll
        for (int s = 0; s < 8; ++s) {
            const int il = w * 8 + s;
            const int n  = il * 2 + (lane >> 5);
            const int p  = lane & 31;
            const int g  = p ^ (n & 15);
            const unsigned short* gp = &kT[((size_t)b * NL + m0 + n) * NC + g * 8];
            __builtin_amdgcn_global_load_lds(
                (const __attribute__((address_space(1))) unsigned int*)gp,
                (__attribute__((address_space(3))) unsigned int*)&Klds[il * 512],
                16, 0, 0);
        }
        #pragma unroll
        for (int s = 0; s < 8; ++s) {
            const int il = w * 8 + s;
            const int c  = il * 8 + (lane >> 3);
            const int p  = lane & 7;
            const int g  = p ^ (c & 7);
            const unsigned short* gp = &v[((size_t)(b * NC + c)) * NL + m0 + g * 8];
            __builtin_amdgcn_global_load_lds(
                (const __attribute__((address_space(1))) unsigned int*)gp,
                (__attribute__((address_space(3))) unsigned int*)&Vlds[il * 512],
                16, 0, 0);
        }
        __syncthreads();

        // ---- S = Q^T K ----
        f32x4 sacc[4];
        #pragma unroll
        for (int nt = 0; nt < 4; ++nt) sacc[nt] = f32x4{0.f, 0.f, 0.f, 0.f};
        #pragma unroll
        for (int nt = 0; nt < 4; ++nt) {
            const int n = nt * 16 + ln15;
            #pragma unroll
            for (int kt = 0; kt < 8; ++kt) {
                const int p = (kt * 4 + quad) ^ ln15;
                bf16x8 bf = __builtin_bit_cast(bf16x8,
                              *(const u32x4*)&Klds[n * 256 + p * 8]);
                sacc[nt] = __builtin_amdgcn_mfma_f32_16x16x32_bf16(
                               qf[kt], bf, sacc[nt], 0, 0, 0);
            }
        }

        // ---- exp, row sums, P -> LDS ----
        float rs[4] = {0.f, 0.f, 0.f, 0.f};
        #pragma unroll
        for (int nt = 0; nt < 4; ++nt) {
            #pragma unroll
            for (int r = 0; r < 4; ++r) {
                float e = __expf(sacc[nt][r] * SCALE);
                rs[r] += e;
                const int ip = w * 16 + quad * 4 + r;
                const int j  = nt * 16 + ln15;
                const int pc = (j >> 3) ^ (ip & 7);
                Plds[ip * 64 + pc * 8 + (j & 7)] = f2b(e);
            }
        }
        #pragma unroll
        for (int r = 0; r < 4; ++r) {
            rs[r] += __shfl_xor(rs[r], 1, 64);
            rs[r] += __shfl_xor(rs[r], 2, 64);
            rs[r] += __shfl_xor(rs[r], 4, 64);
            rs[r] += __shfl_xor(rs[r], 8, 64);
        }
        if (ln15 == 0) {
            #pragma unroll
            for (int r = 0; r < 4; ++r) denom[w * 16 + quad * 4 + r] += rs[r];
        }

        // ---- PV ----
        bf16x8 pf[2];
        {
            const int m = w * 16 + ln15;
            #pragma unroll
            for (int kt = 0; kt < 2; ++kt) {
                const int p = (kt * 4 + quad) ^ (m & 7);
                pf[kt] = __builtin_bit_cast(bf16x8,
                           *(const u32x4*)&Plds[m * 64 + p * 8]);
            }
        }
        #pragma unroll
        for (int ct = 0; ct < 16; ++ct) {
            const int c = ct * 16 + ln15;
            #pragma unroll
            for (int kt = 0; kt < 2; ++kt) {
                const int p = (kt * 4 + quad) ^ (c & 7);
                bf16x8 vb = __builtin_bit_cast(bf16x8,
                              *(const u32x4*)&Vlds[c * 64 + p * 8]);
                ctx[ct] = __builtin_amdgcn_mfma_f32_16x16x32_bf16(
                              pf[kt], vb, ctx[ct], 0, 0, 0);
            }
        }
    }

    // ---- epilogue: normalize, residual, coalesced stores via LDS ----
    __syncthreads();   // all waves done with K-loop before T aliases Klds
    float dinv[4];
    #pragma unroll
    for (int r = 0; r < 4; ++r) dinv[r] = 1.0f / denom[w * 16 + quad * 4 + r];

    const int col  = t & 63;
    const int colg = t >> 6;
    for (int gq = 0; gq < 4; ++gq) {
        __syncthreads();
        #pragma unroll
        for (int ctl = 0; ctl < 4; ++ctl) {
            const int ct = gq * 4 + ctl;
            f32x4 val;
            #pragma unroll
            for (int r = 0; r < 4; ++r) val[r] = ctx[ct][r] * dinv[r];
            *(f32x4*)&T[ctl * 16 + ln15][w * 16 + quad * 4] = val;
        }
        __syncthreads();
        #pragma unroll
        for (int rr = 0; rr < 16; ++rr) {
            const int cl = colg * 16 + rr;
            const size_t idx = ((size_t)(b * NC + gq * 64 + cl)) * NL + l0 + col;
            out[idx] = T[cl][col] + x[idx];
        }
    }
}

// ---------------------------------------------------------------------------
extern "C" void kernel_launch(void* const* d_in, const int* in_sizes, int n_in,
                              void* d_out, int out_size, void* d_ws, size_t ws_size,
                              hipStream_t stream) {
    const float* x  = (const float*)d_in[0];
    const float* Wq = (const float*)d_in[1];
    const float* bq = (const float*)d_in[2];
    const float* Wk = (const float*)d_in[3];
    const float* bk = (const float*)d_in[4];
    const float* Wv = (const float*)d_in[5];
    const float* bv = (const float*)d_in[6];
    float* out = (float*)d_out;

    const size_t plane = (size_t)NB * NC * NL;       // 4.19M elems
    unsigned short* qT  = (unsigned short*)d_ws;
    unsigned short* kT  = qT + plane;
    unsigned short* v   = kT + plane;
    unsigned short* xT  = v + plane;
    unsigned short* Wbf = xT + plane;                // 3*65536 elems

    wconv_kernel<<<192, 256, 0, stream>>>(Wq, Wk, Wv, Wbf);

    dim3 gx(NL / 64, NC / 64, NB);                   // (32, 4, 8)
    xprep_kernel<<<gx, 256, 0, stream>>>(x, xT);

    qkv_mfma<<<768, 256, 0, stream>>>(xT, Wbf, bq, bk, bv, qT, kT, v);

    attn_kernel<<<256, 256, 0, stream>>>(qT, kT, v, x, out);
}